// Round 13
// baseline (55.193 us; speedup 1.0000x reference)
//
#include <hip/hip_runtime.h>

// Laplacian of MLP 3 -> 128(tanh) -> 64(tanh) -> 1 via Taylor jets,
// as 5 f16-MFMA GEMM families + VALU jet construction. Single fused
// kernel, LDS-staged weights, NO d_ws (poison-safe: reads only d_in).
// BLOCK=256, TILES=2, grid ~1024 (R10-verified shape).
//
// DIAGNOSTIC BUILD (R8-pattern, passed pre+post-timing): per-tile BODY
// (acc-init + kk-loop + epilogue) executed REP=3 times with a laundered
// zero folded into x so reps cannot CSE; partial = sum/REP (deterministic,
// <=1 ulp). Purpose: (a) dur = F + 3M updates the fixed/marginal split
// for the CURRENT structure; (b) ~54 us > 41 us harness fills => lap_fused
// tops rocprof top-5 => fresh VALUBusy/MfmaUtil/VGPR for this exact code.
//
// Math per batch element b, with h = tanh(x W1^T + b1), s = 1-h^2:
//   P0[j] = h[j]; Pd[j] = s[j]*W1[j][d]; Ps[j] = h s * (-2 sum_d W1[j][d]^2)
// z_f = P_f @ W2^T (5 families, K=128, 64 outputs), then
//   g0 = tanh(z0+b2), s2 = 1-g0^2
//   G2[k] = s2*zs[k] - 2 g0 s2 * (z1^2+z2^2+z3^2)[k]
//   out[b] = sum_k W3[k]*G2[k]     (b3 never enters the 2nd coefficient)
//
// MFMA: D = A*B, A = W2 tile [16k x 32j] (LDS, frag-ordered), B = jets
// [32j x 16b] (regs). Same assumed lane->k map on both operands => any HW
// k-permutation cancels. C/D: col=lane&15 (b), row=(lane>>4)*4+r (k).
//
// tanh(v) = 1 - 2/(exp2(C*v)+1), C = 2*log2(e), C folded into tables.
//
// NOTE: round-9's f16 pair-table construct stays quarantined (O(1) errors).

typedef _Float16 h2 __attribute__((ext_vector_type(2)));
typedef _Float16 h4 __attribute__((ext_vector_type(4)));
typedef _Float16 h8 __attribute__((ext_vector_type(8)));
typedef float f32x4 __attribute__((ext_vector_type(4)));

#define BLOCK 256
constexpr int DH1 = 128;
constexpr int DH2 = 64;
constexpr int TILES = 2;
constexpr int REP = 3;                            // diagnostic repetition
constexpr float CTANH = 2.885390081777926814f;    // 2*log2(e)

__device__ __forceinline__ h2 pk(float a, float b) {
    auto r = __builtin_amdgcn_cvt_pkrtz(a, b);
    return __builtin_bit_cast(h2, r);
}

__device__ __forceinline__ h8 cat4(h2 a, h2 b, h2 c, h2 d) {
    h4 lo = __builtin_shufflevector(a, b, 0, 1, 2, 3);
    h4 hi = __builtin_shufflevector(c, d, 0, 1, 2, 3);
    return __builtin_shufflevector(lo, hi, 0, 1, 2, 3, 4, 5, 6, 7);
}

__global__ __launch_bounds__(BLOCK) void lap_fused(
        const float* __restrict__ x,
        const float* __restrict__ W1, const float* __restrict__ b1,
        const float* __restrict__ W2, const float* __restrict__ b2,
        const float* __restrict__ W3,
        float* __restrict__ out, int B, int ntiles)
{
    __shared__ float4 s_w1p[DH1];                     // {wx,wy,wz, C*b1}
    __shared__ float  s_wq2[DH1];                     // -2*sum_d W1[j][d]^2
    __shared__ __align__(16) _Float16 s_a[16][64][8]; // [(kk*4+m)][lane][i]
    __shared__ __align__(16) float s_b2c[DH2];        // C*b2
    __shared__ __align__(16) float s_w3[DH2];

    const int t    = threadIdx.x;
    const int lane = t & 63;
    const int wave = t >> 6;
    const int bcol = lane & 15;
    const int g    = lane >> 4;

    // ---- hoist both tiles' x loads (latency hides under setup pack) ----
    float xv[TILES][3];
    #pragma unroll
    for (int tile = 0; tile < TILES; ++tile) {
        const int tid  = blockIdx.x + tile * gridDim.x;
        const int braw = tid * 64 + wave * 16 + bcol;
        const int b    = (braw < B) ? braw : (B - 1);
        xv[tile][0] = x[b*3+0];
        xv[tile][1] = x[b*3+1];
        xv[tile][2] = x[b*3+2];
    }

    // ---- setup (once per block): pack W2 fragments + W1 tables ----
    #pragma unroll
    for (int u = 0; u < 4; ++u) {
        const int f   = u * 256 + t;      // fragment id 0..1023
        const int l   = f & 63;
        const int row = f >> 6;           // kk*4 + m
        const int m   = row & 3;
        const int kk  = row >> 2;
        const int k   = m * 16 + (l & 15);
        const int jr  = kk * 32 + (l >> 4) * 8;
        const float4 wlo = *reinterpret_cast<const float4*>(W2 + k * DH1 + jr);
        const float4 whi = *reinterpret_cast<const float4*>(W2 + k * DH1 + jr + 4);
        *reinterpret_cast<h8*>(&s_a[row][l][0]) =
            cat4(pk(wlo.x, wlo.y), pk(wlo.z, wlo.w),
                 pk(whi.x, whi.y), pk(whi.z, whi.w));
    }
    if (t < DH1) {
        const float wx = W1[t*3+0], wy = W1[t*3+1], wz = W1[t*3+2];
        s_w1p[t] = make_float4(wx, wy, wz, CTANH * b1[t]);
        s_wq2[t] = -2.0f * (wx*wx + wy*wy + wz*wz);
    }
    if (t < DH2) { s_b2c[t] = CTANH * b2[t]; s_w3[t] = W3[t]; }
    __syncthreads();

    #pragma unroll 1
    for (int tile = 0; tile < TILES; ++tile) {
        const int tid = blockIdx.x + tile * gridDim.x;
        if (tid >= ntiles) break;
        const int braw = tid * 64 + wave * 16 + bcol;

        const float x0c = xv[tile][0] * CTANH;
        const float x1c = xv[tile][1] * CTANH;
        const float x2c = xv[tile][2] * CTANH;

        float outacc = 0.0f;

        #pragma unroll 1
        for (int rep = 0; rep < REP; ++rep) {
            // Laundered zero: reps can't CSE; value is identical each rep.
            float zero = 0.0f;
            asm volatile("" : "+v"(zero));
            const float x0r = x0c + zero;
            const float x1r = x1c + zero;
            const float x2r = x2c + zero;

            f32x4 acc[5][4];
            #pragma unroll
            for (int f = 0; f < 5; ++f)
                #pragma unroll
                for (int m = 0; m < 4; ++m)
                    acc[f][m] = (f32x4){0.f, 0.f, 0.f, 0.f};

            #pragma unroll
            for (int kk = 0; kk < 4; ++kk) {
                h2 P0[4], P1[4], P2[4], P3[4], P4[4];
                #pragma unroll
                for (int ii = 0; ii < 4; ++ii) {
                    const int j0 = kk*32 + g*8 + ii*2;
                    const float4 wa = s_w1p[j0];
                    const float4 wb = s_w1p[j0 + 1];
                    const float  qa = s_wq2[j0];
                    const float  qb = s_wq2[j0 + 1];

                    const float prea = fmaf(x0r, wa.x, fmaf(x1r, wa.y, fmaf(x2r, wa.z, wa.w)));
                    const float ea   = __builtin_amdgcn_exp2f(prea);
                    const float ra   = __builtin_amdgcn_rcpf(ea + 1.0f);
                    const float ha   = fmaf(-2.0f, ra, 1.0f);
                    const float sa   = fmaf(-ha, ha, 1.0f);

                    const float preb = fmaf(x0r, wb.x, fmaf(x1r, wb.y, fmaf(x2r, wb.z, wb.w)));
                    const float eb   = __builtin_amdgcn_exp2f(preb);
                    const float rb   = __builtin_amdgcn_rcpf(eb + 1.0f);
                    const float hb   = fmaf(-2.0f, rb, 1.0f);
                    const float sb   = fmaf(-hb, hb, 1.0f);

                    P0[ii] = pk(ha,          hb);
                    P1[ii] = pk(sa * wa.x,   sb * wb.x);
                    P2[ii] = pk(sa * wa.y,   sb * wb.y);
                    P3[ii] = pk(sa * wa.z,   sb * wb.z);
                    P4[ii] = pk((ha*sa)*qa,  (hb*sb)*qb);
                }
                const h8 F0 = cat4(P0[0], P0[1], P0[2], P0[3]);
                const h8 F1 = cat4(P1[0], P1[1], P1[2], P1[3]);
                const h8 F2 = cat4(P2[0], P2[1], P2[2], P2[3]);
                const h8 F3 = cat4(P3[0], P3[1], P3[2], P3[3]);
                const h8 F4 = cat4(P4[0], P4[1], P4[2], P4[3]);

                #pragma unroll
                for (int m = 0; m < 4; ++m) {
                    const h8 fa = *reinterpret_cast<const h8*>(&s_a[kk*4 + m][lane][0]);
                    acc[0][m] = __builtin_amdgcn_mfma_f32_16x16x32_f16(fa, F0, acc[0][m], 0, 0, 0);
                    acc[1][m] = __builtin_amdgcn_mfma_f32_16x16x32_f16(fa, F1, acc[1][m], 0, 0, 0);
                    acc[2][m] = __builtin_amdgcn_mfma_f32_16x16x32_f16(fa, F2, acc[2][m], 0, 0, 0);
                    acc[3][m] = __builtin_amdgcn_mfma_f32_16x16x32_f16(fa, F3, acc[3][m], 0, 0, 0);
                    acc[4][m] = __builtin_amdgcn_mfma_f32_16x16x32_f16(fa, F4, acc[4][m], 0, 0, 0);
                }
            }

            float partial = 0.0f;
            #pragma unroll
            for (int m = 0; m < 4; ++m) {
                const int kb = m*16 + g*4;
                const f32x4 b2v = *reinterpret_cast<const f32x4*>(&s_b2c[kb]);
                const f32x4 w3v = *reinterpret_cast<const f32x4*>(&s_w3[kb]);
                #pragma unroll
                for (int r = 0; r < 4; ++r) {
                    const float e0 = __builtin_amdgcn_exp2f(fmaf(CTANH, acc[0][m][r], b2v[r]));
                    const float g0 = fmaf(-2.0f, __builtin_amdgcn_rcpf(e0 + 1.0f), 1.0f);
                    const float s2 = fmaf(-g0, g0, 1.0f);
                    const float qd = acc[1][m][r]*acc[1][m][r]
                                   + acc[2][m][r]*acc[2][m][r]
                                   + acc[3][m][r]*acc[3][m][r];
                    const float G2 = s2 * fmaf(-2.0f * g0, qd, acc[4][m][r]);
                    partial = fmaf(w3v[r], G2, partial);
                }
            }
            outacc += partial;
        }

        float partial = outacc * (1.0f / (float)REP);
        partial += __shfl_xor(partial, 16);
        partial += __shfl_xor(partial, 32);

        if (g == 0 && braw < B) out[braw] = partial;
    }
}

extern "C" void kernel_launch(void* const* d_in, const int* in_sizes, int n_in,
                              void* d_out, int out_size, void* d_ws, size_t ws_size,
                              hipStream_t stream) {
    const float* x  = (const float*)d_in[0];
    const float* W1 = (const float*)d_in[1];
    const float* b1 = (const float*)d_in[2];
    const float* W2 = (const float*)d_in[3];
    const float* b2 = (const float*)d_in[4];
    const float* W3 = (const float*)d_in[5];
    // d_in[6] = b3: does not enter the 2nd Taylor coefficient.
    float* out = (float*)d_out;

    const int B      = in_sizes[0] / 3;
    const int ntiles = (B + 63) / 64;
    const int grid   = (ntiles + TILES - 1) / TILES;
    lap_fused<<<grid, BLOCK, 0, stream>>>(x, W1, b1, W2, b2, W3, out, B, ntiles);
}

// Round 15
// 24.829 us; speedup vs baseline: 2.2229x; 2.2229x over previous
//
#include <hip/hip_runtime.h>

// Laplacian of MLP 3 -> 128(tanh) -> 64(tanh) -> 1 via Taylor jets,
// as 5 f16-MFMA GEMM families + VALU jet construction. Single fused
// kernel, LDS-staged weights, NO d_ws (poison-safe: reads only d_in).
// BLOCK=256, TILES=2, grid ~1024 (R10-verified shape; R11: fewer/fatter
// blocks regressed 41% -> keep >=4 blocks/CU).
//
// Math per batch element b, with h = tanh(x W1^T + b1), s = 1-h^2:
//   P0[j] = h[j]; Pd[j] = s[j]*W1[j][d]; Ps[j] = h s * (-2 sum_d W1[j][d]^2)
// z_f = P_f @ W2^T (5 families, K=128, 64 outputs), then
//   g0 = tanh(z0+b2), s2 = 1-g0^2
//   G2[k] = s2*zs[k] - 2 g0 s2 * (z1^2+z2^2+z3^2)[k]
//   out[b] = sum_k W3[k]*G2[k]     (b3 never enters the 2nd coefficient)
//
// MFMA: D = A*B, A = W2 tile [16k x 32j] (LDS, frag-ordered), B = jets
// [32j x 16b] (regs). Same assumed lane->k map on both operands => any HW
// k-permutation cancels. C/D: col=lane&15 (b), row=(lane>>4)*4+r (k).
//
// R9/R14 forensics: both packed-f16-multiply attempts failed with the
// IDENTICAL absmax (2.195) across two different table layouts => the h2
// ext_vector operator* lowering is the deterministic culprit, not the
// table. THIS ROUND: bypass clang's h2 arithmetic with inline-asm
// v_pk_mul_f16 (VOP3P default op_sel = {lo*lo, hi*hi}). Everything else
// is bit-identical to the R12 winner (separate rcp kept — isolation).
//
// tanh(v) = 1 - 2/(exp2(C*v)+1), C = 2*log2(e), C folded into tables.

typedef _Float16 h2 __attribute__((ext_vector_type(2)));
typedef _Float16 h4 __attribute__((ext_vector_type(4)));
typedef _Float16 h8 __attribute__((ext_vector_type(8)));
typedef float f32x4 __attribute__((ext_vector_type(4)));

#define BLOCK 256
constexpr int DH1 = 128;
constexpr int DH2 = 64;
constexpr int TILES = 2;
constexpr float CTANH = 2.885390081777926814f;   // 2*log2(e)

__device__ __forceinline__ h2 pk(float a, float b) {
    auto r = __builtin_amdgcn_cvt_pkrtz(a, b);
    return __builtin_bit_cast(h2, r);
}

__device__ __forceinline__ float pkf(float a, float b) {
    return __builtin_bit_cast(float, __builtin_amdgcn_cvt_pkrtz(a, b));
}

// Packed f16 multiply via raw VOP3P instruction — bypasses clang's h2
// operator* lowering (R9/R14 failure suspect). {lo*lo, hi*hi}.
__device__ __forceinline__ h2 pkmul(h2 a, float bbits) {
    float af = __builtin_bit_cast(float, a);
    float r;
    asm("v_pk_mul_f16 %0, %1, %2" : "=v"(r) : "v"(af), "v"(bbits));
    return __builtin_bit_cast(h2, r);
}

__device__ __forceinline__ h8 cat4(h2 a, h2 b, h2 c, h2 d) {
    h4 lo = __builtin_shufflevector(a, b, 0, 1, 2, 3);
    h4 hi = __builtin_shufflevector(c, d, 0, 1, 2, 3);
    return __builtin_shufflevector(lo, hi, 0, 1, 2, 3, 4, 5, 6, 7);
}

__global__ __launch_bounds__(BLOCK) void lap_fused(
        const float* __restrict__ x,
        const float* __restrict__ W1, const float* __restrict__ b1,
        const float* __restrict__ W2, const float* __restrict__ b2,
        const float* __restrict__ W3,
        float* __restrict__ out, int B, int ntiles)
{
    __shared__ float4 s_w1p[DH1];                     // {wx,wy,wz, C*b1}
    __shared__ f32x4  s_wpk[DH1/2];                   // {pk(wx),pk(wy),pk(wz),pk(q)} per j-pair
    __shared__ __align__(16) _Float16 s_a[16][64][8]; // [(kk*4+m)][lane][i]
    __shared__ __align__(16) float s_b2c[DH2];        // C*b2
    __shared__ __align__(16) float s_w3[DH2];

    const int t    = threadIdx.x;
    const int lane = t & 63;
    const int wave = t >> 6;
    const int bcol = lane & 15;
    const int g    = lane >> 4;

    // ---- hoist both tiles' x loads (latency hides under setup pack) ----
    float xv[TILES][3];
    #pragma unroll
    for (int tile = 0; tile < TILES; ++tile) {
        const int tid  = blockIdx.x + tile * gridDim.x;
        const int braw = tid * 64 + wave * 16 + bcol;
        const int b    = (braw < B) ? braw : (B - 1);
        xv[tile][0] = x[b*3+0];
        xv[tile][1] = x[b*3+1];
        xv[tile][2] = x[b*3+2];
    }

    // ---- setup (once per block): pack W2 fragments + W1 tables ----
    #pragma unroll
    for (int u = 0; u < 4; ++u) {
        const int f   = u * 256 + t;      // fragment id 0..1023
        const int l   = f & 63;
        const int row = f >> 6;           // kk*4 + m
        const int m   = row & 3;
        const int kk  = row >> 2;
        const int k   = m * 16 + (l & 15);
        const int jr  = kk * 32 + (l >> 4) * 8;
        const float4 wlo = *reinterpret_cast<const float4*>(W2 + k * DH1 + jr);
        const float4 whi = *reinterpret_cast<const float4*>(W2 + k * DH1 + jr + 4);
        *reinterpret_cast<h8*>(&s_a[row][l][0]) =
            cat4(pk(wlo.x, wlo.y), pk(wlo.z, wlo.w),
                 pk(whi.x, whi.y), pk(whi.z, whi.w));
    }
    if (t < DH1) {
        const float wx = W1[t*3+0], wy = W1[t*3+1], wz = W1[t*3+2];
        s_w1p[t] = make_float4(wx, wy, wz, CTANH * b1[t]);
    }
    if (t < DH1/2) {   // packed pair table: f32x4 written AND read
        const float wxe = W1[6*t+0], wye = W1[6*t+1], wze = W1[6*t+2];
        const float wxo = W1[6*t+3], wyo = W1[6*t+4], wzo = W1[6*t+5];
        const float qe  = -2.0f * (wxe*wxe + wye*wye + wze*wze);
        const float qo  = -2.0f * (wxo*wxo + wyo*wyo + wzo*wzo);
        f32x4 v;
        v[0] = pkf(wxe, wxo);
        v[1] = pkf(wye, wyo);
        v[2] = pkf(wze, wzo);
        v[3] = pkf(qe,  qo);
        s_wpk[t] = v;
    }
    if (t < DH2) { s_b2c[t] = CTANH * b2[t]; s_w3[t] = W3[t]; }
    __syncthreads();

    #pragma unroll 1
    for (int tile = 0; tile < TILES; ++tile) {
        const int tid = blockIdx.x + tile * gridDim.x;   // batch-tile index
        if (tid >= ntiles) break;
        const int braw = tid * 64 + wave * 16 + bcol;

        const float x0c = xv[tile][0] * CTANH;
        const float x1c = xv[tile][1] * CTANH;
        const float x2c = xv[tile][2] * CTANH;

        f32x4 acc[5][4];
        #pragma unroll
        for (int f = 0; f < 5; ++f)
            #pragma unroll
            for (int m = 0; m < 4; ++m)
                acc[f][m] = (f32x4){0.f, 0.f, 0.f, 0.f};

        #pragma unroll
        for (int kk = 0; kk < 4; ++kk) {
            // ---- jets for this lane's 8 j's (4 independent pairs) ----
            h2 P0[4], P1[4], P2[4], P3[4], P4[4];
            #pragma unroll
            for (int ii = 0; ii < 4; ++ii) {
                const int j0 = kk*32 + g*8 + ii*2;
                const float4 wa = s_w1p[j0];
                const float4 wb = s_w1p[j0 + 1];
                const f32x4  wp = s_wpk[j0 >> 1];

                // pre = C*(x.w1 + b1); tanh = 1 - 2*rcp(exp2(pre)+1)
                const float prea = fmaf(x0c, wa.x, fmaf(x1c, wa.y, fmaf(x2c, wa.z, wa.w)));
                const float ea   = __builtin_amdgcn_exp2f(prea);
                const float ra   = __builtin_amdgcn_rcpf(ea + 1.0f);
                const float ha   = fmaf(-2.0f, ra, 1.0f);
                const float sa   = fmaf(-ha, ha, 1.0f);

                const float preb = fmaf(x0c, wb.x, fmaf(x1c, wb.y, fmaf(x2c, wb.z, wb.w)));
                const float eb   = __builtin_amdgcn_exp2f(preb);
                const float rb   = __builtin_amdgcn_rcpf(eb + 1.0f);
                const float hb   = fmaf(-2.0f, rb, 1.0f);
                const float sb   = fmaf(-hb, hb, 1.0f);

                const h2 S  = pk(sa, sb);
                const h2 HS = pk(ha * sa, hb * sb);
                P0[ii] = pk(ha, hb);
                P1[ii] = pkmul(S,  wp[0]);   // v_pk_mul_f16 via asm
                P2[ii] = pkmul(S,  wp[1]);
                P3[ii] = pkmul(S,  wp[2]);
                P4[ii] = pkmul(HS, wp[3]);
            }
            const h8 F0 = cat4(P0[0], P0[1], P0[2], P0[3]);
            const h8 F1 = cat4(P1[0], P1[1], P1[2], P1[3]);
            const h8 F2 = cat4(P2[0], P2[1], P2[2], P2[3]);
            const h8 F3 = cat4(P3[0], P3[1], P3[2], P3[3]);
            const h8 F4 = cat4(P4[0], P4[1], P4[2], P4[3]);

            #pragma unroll
            for (int m = 0; m < 4; ++m) {
                const h8 fa = *reinterpret_cast<const h8*>(&s_a[kk*4 + m][lane][0]);
                acc[0][m] = __builtin_amdgcn_mfma_f32_16x16x32_f16(fa, F0, acc[0][m], 0, 0, 0);
                acc[1][m] = __builtin_amdgcn_mfma_f32_16x16x32_f16(fa, F1, acc[1][m], 0, 0, 0);
                acc[2][m] = __builtin_amdgcn_mfma_f32_16x16x32_f16(fa, F2, acc[2][m], 0, 0, 0);
                acc[3][m] = __builtin_amdgcn_mfma_f32_16x16x32_f16(fa, F3, acc[3][m], 0, 0, 0);
                acc[4][m] = __builtin_amdgcn_mfma_f32_16x16x32_f16(fa, F4, acc[4][m], 0, 0, 0);
            }
        }

        // ---- epilogue: lane holds k = m*16 + g*4 + r for its batch column ----
        float partial = 0.0f;
        #pragma unroll
        for (int m = 0; m < 4; ++m) {
            const int kb = m*16 + g*4;
            const f32x4 b2v = *reinterpret_cast<const f32x4*>(&s_b2c[kb]);
            const f32x4 w3v = *reinterpret_cast<const f32x4*>(&s_w3[kb]);
            #pragma unroll
            for (int r = 0; r < 4; ++r) {
                // g0 = tanh(z0 + b2): arg = C*acc + C*b2 (folded)
                const float e0 = __builtin_amdgcn_exp2f(fmaf(CTANH, acc[0][m][r], b2v[r]));
                const float g0 = fmaf(-2.0f, __builtin_amdgcn_rcpf(e0 + 1.0f), 1.0f);
                const float s2 = fmaf(-g0, g0, 1.0f);
                const float qd = acc[1][m][r]*acc[1][m][r]
                               + acc[2][m][r]*acc[2][m][r]
                               + acc[3][m][r]*acc[3][m][r];
                const float G2 = s2 * fmaf(-2.0f * g0, qd, acc[4][m][r]);
                partial = fmaf(w3v[r], G2, partial);
            }
        }

        partial += __shfl_xor(partial, 16);
        partial += __shfl_xor(partial, 32);

        if (g == 0 && braw < B) out[braw] = partial;
    }
}

extern "C" void kernel_launch(void* const* d_in, const int* in_sizes, int n_in,
                              void* d_out, int out_size, void* d_ws, size_t ws_size,
                              hipStream_t stream) {
    const float* x  = (const float*)d_in[0];
    const float* W1 = (const float*)d_in[1];
    const float* b1 = (const float*)d_in[2];
    const float* W2 = (const float*)d_in[3];
    const float* b2 = (const float*)d_in[4];
    const float* W3 = (const float*)d_in[5];
    // d_in[6] = b3: does not enter the 2nd Taylor coefficient.
    float* out = (float*)d_out;

    const int B      = in_sizes[0] / 3;
    const int ntiles = (B + 63) / 64;                // 64 batch per tile
    const int grid   = (ntiles + TILES - 1) / TILES; // ~1024 blocks
    lap_fused<<<grid, BLOCK, 0, stream>>>(x, W1, b1, W2, b2, W3, out, B, ntiles);
}

// Round 16
// 23.750 us; speedup vs baseline: 2.3239x; 1.0454x over previous
//
#include <hip/hip_runtime.h>

// Laplacian of MLP 3 -> 128(tanh) -> 64(tanh) -> 1 via Taylor jets,
// as 5 f16-MFMA GEMM families + VALU jet construction. Single fused
// kernel, LDS-staged weights, NO d_ws (poison-safe: reads only d_in).
// BLOCK=256, TILES=2, grid ~1024 (R10-verified shape).
//
// Math per batch element b, with h = tanh(x W1^T + b1), s = 1-h^2:
//   P0[j] = h[j]; Pd[j] = s[j]*W1[j][d]; Ps[j] = h s * (-2 sum_d W1[j][d]^2)
// z_f = P_f @ W2^T (5 families, K=128, 64 outputs), then
//   g0 = tanh(z0+b2), s2 = 1-g0^2
//   G2[k] = s2*zs[k] - 2 g0 s2 * (z1^2+z2^2+z3^2)[k]
//   out[b] = sum_k W3[k]*G2[k]     (b3 never enters the 2nd coefficient)
//
// NEW (R16): layer-1 pre-activation via MFMA. pre = C*(x.W1^T + b1) is a
// K=4 GEMM run as 2 zero-padded 16x16x32 MFMAs per kk (A1 = {wx,wy,wz,
// C*b1} f16 on k-slots 0..3 of lane-group g=0; B1 = {x0c,x1c,x2c,1}).
// The pre-GEMM's D-layout (lane holds j = m1*16+g*4+r, col=bcol) is
// ADOPTED as the main GEMM's k-map: F(lane,i) = (2kk+(i>>2))*16+g*4+(i&3)
// on BOTH the A-pack (setup-time indexing) and the B jet slots, so the
// HW k-permutation still cancels and pre feeds jets with no cross-lane
// data movement. Kills 96 f32 FMA + 32 ds_read_b128 per tile (s_w1p is
// gone) for +8 MFMA +8 ds_read.
//
// R9/R14 forensics: clang's h2 ext_vector operator* miscompiles (identical
// absmax 2.195 across two layouts); R15 proved inline-asm v_pk_mul_f16
// works. Keep pkmul asm; never use h2 operator*.
//
// tanh(v) = 1 - 2/(exp2(C*v)+1), C = 2*log2(e), C folded into tables.

typedef _Float16 h2 __attribute__((ext_vector_type(2)));
typedef _Float16 h4 __attribute__((ext_vector_type(4)));
typedef _Float16 h8 __attribute__((ext_vector_type(8)));
typedef float f32x4 __attribute__((ext_vector_type(4)));

#define BLOCK 256
constexpr int DH1 = 128;
constexpr int DH2 = 64;
constexpr int TILES = 2;
constexpr float CTANH = 2.885390081777926814f;   // 2*log2(e)

__device__ __forceinline__ h2 pk(float a, float b) {
    auto r = __builtin_amdgcn_cvt_pkrtz(a, b);
    return __builtin_bit_cast(h2, r);
}

__device__ __forceinline__ float pkf(float a, float b) {
    return __builtin_bit_cast(float, __builtin_amdgcn_cvt_pkrtz(a, b));
}

// Packed f16 multiply via raw VOP3P — bypasses clang's broken h2 operator*
// (R9/R14: deterministic miscompile). {lo*lo, hi*hi}.
__device__ __forceinline__ h2 pkmul(h2 a, float bbits) {
    float af = __builtin_bit_cast(float, a);
    float r;
    asm("v_pk_mul_f16 %0, %1, %2" : "=v"(r) : "v"(af), "v"(bbits));
    return __builtin_bit_cast(h2, r);
}

__device__ __forceinline__ h8 cat4(h2 a, h2 b, h2 c, h2 d) {
    h4 lo = __builtin_shufflevector(a, b, 0, 1, 2, 3);
    h4 hi = __builtin_shufflevector(c, d, 0, 1, 2, 3);
    return __builtin_shufflevector(lo, hi, 0, 1, 2, 3, 4, 5, 6, 7);
}

__global__ __launch_bounds__(BLOCK) void lap_fused(
        const float* __restrict__ x,
        const float* __restrict__ W1, const float* __restrict__ b1,
        const float* __restrict__ W2, const float* __restrict__ b2,
        const float* __restrict__ W3,
        float* __restrict__ out, int B, int ntiles)
{
    __shared__ __align__(16) _Float16 s_a [16][64][8]; // main A: [(kk*4+m)][lane][i]
    __shared__ __align__(16) _Float16 s_a1[ 8][64][8]; // pre  A: [m1][lane][i]
    __shared__ f32x4  s_wpk[DH1/2];                    // {pk(wx),pk(wy),pk(wz),pk(q)} per j-pair
    __shared__ __align__(16) float s_b2c[DH2];         // C*b2
    __shared__ __align__(16) float s_w3[DH2];

    const int t    = threadIdx.x;
    const int lane = t & 63;
    const int wave = t >> 6;
    const int bcol = lane & 15;
    const int g    = lane >> 4;

    // ---- hoist both tiles' x loads (latency hides under setup pack) ----
    float xv[TILES][3];
    #pragma unroll
    for (int tile = 0; tile < TILES; ++tile) {
        const int tid  = blockIdx.x + tile * gridDim.x;
        const int braw = tid * 64 + wave * 16 + bcol;
        const int b    = (braw < B) ? braw : (B - 1);
        xv[tile][0] = x[b*3+0];
        xv[tile][1] = x[b*3+1];
        xv[tile][2] = x[b*3+2];
    }

    // ---- setup (once per block) ----
    // Main A-pack with the NEW k-map: slot i of lane l (group g_l) holds
    // W2[k][ (kk*2 + (i>>2))*16 + g_l*4 + (i&3) ].
    #pragma unroll
    for (int u = 0; u < 4; ++u) {
        const int f   = u * 256 + t;      // fragment id 0..1023
        const int l   = f & 63;
        const int row = f >> 6;           // kk*4 + m
        const int m   = row & 3;
        const int kk  = row >> 2;
        const int k   = m * 16 + (l & 15);
        const int gl  = l >> 4;
        const int j0  = kk * 32 + gl * 4;        // slots 0..3
        const int j1  = kk * 32 + 16 + gl * 4;   // slots 4..7
        const float4 w0 = *reinterpret_cast<const float4*>(W2 + k * DH1 + j0);
        const float4 w1 = *reinterpret_cast<const float4*>(W2 + k * DH1 + j1);
        *reinterpret_cast<h8*>(&s_a[row][l][0]) =
            cat4(pk(w0.x, w0.y), pk(w0.z, w0.w),
                 pk(w1.x, w1.y), pk(w1.z, w1.w));
    }
    // Pre-GEMM A1-pack: lane-group 0 carries k-slots 0..3 = {wx,wy,wz,C*b1}
    // for row j' = m1*16 + (lane&15); all other groups/slots are zero.
    {
        const h2 z2 = pk(0.0f, 0.0f);
        #pragma unroll
        for (int v = 0; v < 2; ++v) {
            const int e  = v * 256 + t;       // 0..511
            const int m1 = e >> 6;
            const int l  = e & 63;
            const int gl = l >> 4;
            const int jp = m1 * 16 + (l & 15);
            h8 frag;
            if (gl == 0) {
                const float wx = W1[jp*3+0], wy = W1[jp*3+1], wz = W1[jp*3+2];
                frag = cat4(pk(wx, wy), pk(wz, CTANH * b1[jp]), z2, z2);
            } else {
                frag = cat4(z2, z2, z2, z2);
            }
            *reinterpret_cast<h8*>(&s_a1[m1][l][0]) = frag;
        }
    }
    if (t < DH1/2) {   // packed pair table: f32x4 written AND read
        const float wxe = W1[6*t+0], wye = W1[6*t+1], wze = W1[6*t+2];
        const float wxo = W1[6*t+3], wyo = W1[6*t+4], wzo = W1[6*t+5];
        const float qe  = -2.0f * (wxe*wxe + wye*wye + wze*wze);
        const float qo  = -2.0f * (wxo*wxo + wyo*wyo + wzo*wzo);
        f32x4 v;
        v[0] = pkf(wxe, wxo);
        v[1] = pkf(wye, wyo);
        v[2] = pkf(wze, wzo);
        v[3] = pkf(qe,  qo);
        s_wpk[t] = v;
    }
    if (t < DH2) { s_b2c[t] = CTANH * b2[t]; s_w3[t] = W3[t]; }
    __syncthreads();

    #pragma unroll 1
    for (int tile = 0; tile < TILES; ++tile) {
        const int tid = blockIdx.x + tile * gridDim.x;   // batch-tile index
        if (tid >= ntiles) break;
        const int braw = tid * 64 + wave * 16 + bcol;

        const float x0c = xv[tile][0] * CTANH;
        const float x1c = xv[tile][1] * CTANH;
        const float x2c = xv[tile][2] * CTANH;

        // B1 fragment for the pre-GEMM: k-slots 0..3 = {x0c,x1c,x2c,1} on
        // lane-group 0 only (matches A1's zero padding; k-map cancels).
        const h2 z2 = pk(0.0f, 0.0f);
        h2 xlo = z2, xhi = z2;
        if (g == 0) { xlo = pk(x0c, x1c); xhi = pk(x2c, 1.0f); }
        const h8 B1 = cat4(xlo, xhi, z2, z2);

        f32x4 acc[5][4];
        #pragma unroll
        for (int f = 0; f < 5; ++f)
            #pragma unroll
            for (int m = 0; m < 4; ++m)
                acc[f][m] = (f32x4){0.f, 0.f, 0.f, 0.f};

        #pragma unroll
        for (int kk = 0; kk < 4; ++kk) {
            // ---- pre via MFMA + jets for this lane's 8 j's ----
            h2 P0[4], P1[4], P2[4], P3[4], P4[4];
            #pragma unroll
            for (int u = 0; u < 2; ++u) {
                const int m1 = kk*2 + u;
                const h8 fa1 = *reinterpret_cast<const h8*>(&s_a1[m1][lane][0]);
                const f32x4 pr = __builtin_amdgcn_mfma_f32_16x16x32_f16(
                    fa1, B1, (f32x4){0.f, 0.f, 0.f, 0.f}, 0, 0, 0);
                // lane holds pre for j = m1*16 + g*4 + r (r=0..3), col=bcol
                #pragma unroll
                for (int v = 0; v < 2; ++v) {
                    const int pi = u*2 + v;
                    const f32x4 wp = s_wpk[m1*8 + g*2 + v];

                    const float prea = pr[v*2+0];
                    const float preb = pr[v*2+1];
                    const float ea   = __builtin_amdgcn_exp2f(prea);
                    const float ra   = __builtin_amdgcn_rcpf(ea + 1.0f);
                    const float ha   = fmaf(-2.0f, ra, 1.0f);
                    const float sa   = fmaf(-ha, ha, 1.0f);
                    const float eb   = __builtin_amdgcn_exp2f(preb);
                    const float rb   = __builtin_amdgcn_rcpf(eb + 1.0f);
                    const float hb   = fmaf(-2.0f, rb, 1.0f);
                    const float sb   = fmaf(-hb, hb, 1.0f);

                    const h2 S  = pk(sa, sb);
                    const h2 HS = pk(ha * sa, hb * sb);
                    P0[pi] = pk(ha, hb);
                    P1[pi] = pkmul(S,  wp[0]);   // v_pk_mul_f16 via asm
                    P2[pi] = pkmul(S,  wp[1]);
                    P3[pi] = pkmul(S,  wp[2]);
                    P4[pi] = pkmul(HS, wp[3]);
                }
            }
            const h8 F0 = cat4(P0[0], P0[1], P0[2], P0[3]);
            const h8 F1 = cat4(P1[0], P1[1], P1[2], P1[3]);
            const h8 F2 = cat4(P2[0], P2[1], P2[2], P2[3]);
            const h8 F3 = cat4(P3[0], P3[1], P3[2], P3[3]);
            const h8 F4 = cat4(P4[0], P4[1], P4[2], P4[3]);

            #pragma unroll
            for (int m = 0; m < 4; ++m) {
                const h8 fa = *reinterpret_cast<const h8*>(&s_a[kk*4 + m][lane][0]);
                acc[0][m] = __builtin_amdgcn_mfma_f32_16x16x32_f16(fa, F0, acc[0][m], 0, 0, 0);
                acc[1][m] = __builtin_amdgcn_mfma_f32_16x16x32_f16(fa, F1, acc[1][m], 0, 0, 0);
                acc[2][m] = __builtin_amdgcn_mfma_f32_16x16x32_f16(fa, F2, acc[2][m], 0, 0, 0);
                acc[3][m] = __builtin_amdgcn_mfma_f32_16x16x32_f16(fa, F3, acc[3][m], 0, 0, 0);
                acc[4][m] = __builtin_amdgcn_mfma_f32_16x16x32_f16(fa, F4, acc[4][m], 0, 0, 0);
            }
        }

        // ---- epilogue: lane holds k = m*16 + g*4 + r for its batch column ----
        float partial = 0.0f;
        #pragma unroll
        for (int m = 0; m < 4; ++m) {
            const int kb = m*16 + g*4;
            const f32x4 b2v = *reinterpret_cast<const f32x4*>(&s_b2c[kb]);
            const f32x4 w3v = *reinterpret_cast<const f32x4*>(&s_w3[kb]);
            #pragma unroll
            for (int r = 0; r < 4; ++r) {
                // g0 = tanh(z0 + b2): arg = C*acc + C*b2 (folded)
                const float e0 = __builtin_amdgcn_exp2f(fmaf(CTANH, acc[0][m][r], b2v[r]));
                const float g0 = fmaf(-2.0f, __builtin_amdgcn_rcpf(e0 + 1.0f), 1.0f);
                const float s2 = fmaf(-g0, g0, 1.0f);
                const float qd = acc[1][m][r]*acc[1][m][r]
                               + acc[2][m][r]*acc[2][m][r]
                               + acc[3][m][r]*acc[3][m][r];
                const float G2 = s2 * fmaf(-2.0f * g0, qd, acc[4][m][r]);
                partial = fmaf(w3v[r], G2, partial);
            }
        }

        partial += __shfl_xor(partial, 16);
        partial += __shfl_xor(partial, 32);

        if (g == 0 && braw < B) out[braw] = partial;
    }
}

extern "C" void kernel_launch(void* const* d_in, const int* in_sizes, int n_in,
                              void* d_out, int out_size, void* d_ws, size_t ws_size,
                              hipStream_t stream) {
    const float* x  = (const float*)d_in[0];
    const float* W1 = (const float*)d_in[1];
    const float* b1 = (const float*)d_in[2];
    const float* W2 = (const float*)d_in[3];
    const float* b2 = (const float*)d_in[4];
    const float* W3 = (const float*)d_in[5];
    // d_in[6] = b3: does not enter the 2nd Taylor coefficient.
    float* out = (float*)d_out;

    const int B      = in_sizes[0] / 3;
    const int ntiles = (B + 63) / 64;                // 64 batch per tile
    const int grid   = (ntiles + TILES - 1) / TILES; // ~1024 blocks
    lap_fused<<<grid, BLOCK, 0, stream>>>(x, W1, b1, W2, b2, W3, out, B, ntiles);
}

// Round 17
// 23.376 us; speedup vs baseline: 2.3611x; 1.0160x over previous
//
#include <hip/hip_runtime.h>

// Laplacian of MLP 3 -> 128(tanh) -> 64(tanh) -> 1 via Taylor jets,
// as 5 f16-MFMA GEMM families + VALU jet construction. Single fused
// kernel, LDS-staged weights, NO d_ws (poison-safe: reads only d_in).
//
// R17: TILES=4, BLOCK=256, grid=512 (2 blocks/CU, all co-resident at
// VGPR~100). Tests R11's open question: was the 512-thread regression
// the 8-wave barrier (then this wins ~-1.3us: 512 setups vs 1024) or
// 2-blocks/CU granularity (then this regresses and TILES=2 is final)?
//
// Math per batch element b, with h = tanh(x W1^T + b1), s = 1-h^2:
//   P0[j] = h[j]; Pd[j] = s[j]*W1[j][d]; Ps[j] = h s * (-2 sum_d W1[j][d]^2)
// z_f = P_f @ W2^T (5 families, K=128, 64 outputs), then
//   g0 = tanh(z0+b2), s2 = 1-g0^2
//   G2[k] = s2*zs[k] - 2 g0 s2 * (z1^2+z2^2+z3^2)[k]
//   out[b] = sum_k W3[k]*G2[k]     (b3 never enters the 2nd coefficient)
//
// Layer-1 pre via MFMA (R16): pre = C*(x.W1^T+b1) as 2 zero-padded
// 16x16x32 MFMAs per kk; its D-layout is adopted as the main GEMM's
// k-map on BOTH operands (HW permutation cancels), so pre feeds jets
// with zero cross-lane movement.
//
// R9/R14 forensics: clang's h2 ext_vector operator* miscompiles
// (identical absmax 2.195 across layouts); R15 proved inline-asm
// v_pk_mul_f16 works. Keep pkmul asm; never use h2 operator*.
//
// tanh(v) = 1 - 2/(exp2(C*v)+1), C = 2*log2(e), C folded into tables.

typedef _Float16 h2 __attribute__((ext_vector_type(2)));
typedef _Float16 h4 __attribute__((ext_vector_type(4)));
typedef _Float16 h8 __attribute__((ext_vector_type(8)));
typedef float f32x4 __attribute__((ext_vector_type(4)));

#define BLOCK 256
constexpr int DH1 = 128;
constexpr int DH2 = 64;
constexpr int TILES = 4;
constexpr float CTANH = 2.885390081777926814f;   // 2*log2(e)

__device__ __forceinline__ h2 pk(float a, float b) {
    auto r = __builtin_amdgcn_cvt_pkrtz(a, b);
    return __builtin_bit_cast(h2, r);
}

__device__ __forceinline__ float pkf(float a, float b) {
    return __builtin_bit_cast(float, __builtin_amdgcn_cvt_pkrtz(a, b));
}

// Packed f16 multiply via raw VOP3P — bypasses clang's broken h2 operator*
// (R9/R14: deterministic miscompile). {lo*lo, hi*hi}.
__device__ __forceinline__ h2 pkmul(h2 a, float bbits) {
    float af = __builtin_bit_cast(float, a);
    float r;
    asm("v_pk_mul_f16 %0, %1, %2" : "=v"(r) : "v"(af), "v"(bbits));
    return __builtin_bit_cast(h2, r);
}

__device__ __forceinline__ h8 cat4(h2 a, h2 b, h2 c, h2 d) {
    h4 lo = __builtin_shufflevector(a, b, 0, 1, 2, 3);
    h4 hi = __builtin_shufflevector(c, d, 0, 1, 2, 3);
    return __builtin_shufflevector(lo, hi, 0, 1, 2, 3, 4, 5, 6, 7);
}

__global__ __launch_bounds__(BLOCK) void lap_fused(
        const float* __restrict__ x,
        const float* __restrict__ W1, const float* __restrict__ b1,
        const float* __restrict__ W2, const float* __restrict__ b2,
        const float* __restrict__ W3,
        float* __restrict__ out, int B, int ntiles)
{
    __shared__ __align__(16) _Float16 s_a [16][64][8]; // main A: [(kk*4+m)][lane][i]
    __shared__ __align__(16) _Float16 s_a1[ 8][64][8]; // pre  A: [m1][lane][i]
    __shared__ f32x4  s_wpk[DH1/2];                    // {pk(wx),pk(wy),pk(wz),pk(q)} per j-pair
    __shared__ __align__(16) float s_b2c[DH2];         // C*b2
    __shared__ __align__(16) float s_w3[DH2];

    const int t    = threadIdx.x;
    const int lane = t & 63;
    const int wave = t >> 6;
    const int bcol = lane & 15;
    const int g    = lane >> 4;

    // ---- hoist all tiles' x loads (latency hides under setup pack) ----
    float xv[TILES][3];
    #pragma unroll
    for (int tile = 0; tile < TILES; ++tile) {
        const int tid  = blockIdx.x + tile * gridDim.x;
        const int braw = tid * 64 + wave * 16 + bcol;
        const int b    = (braw < B) ? braw : (B - 1);
        xv[tile][0] = x[b*3+0];
        xv[tile][1] = x[b*3+1];
        xv[tile][2] = x[b*3+2];
    }

    // ---- setup (once per block) ----
    // Main A-pack with the adopted k-map: slot i of lane l (group g_l)
    // holds W2[k][ (kk*2 + (i>>2))*16 + g_l*4 + (i&3) ].
    #pragma unroll
    for (int u = 0; u < 4; ++u) {
        const int f   = u * 256 + t;      // fragment id 0..1023
        const int l   = f & 63;
        const int row = f >> 6;           // kk*4 + m
        const int m   = row & 3;
        const int kk  = row >> 2;
        const int k   = m * 16 + (l & 15);
        const int gl  = l >> 4;
        const int j0  = kk * 32 + gl * 4;        // slots 0..3
        const int j1  = kk * 32 + 16 + gl * 4;   // slots 4..7
        const float4 w0 = *reinterpret_cast<const float4*>(W2 + k * DH1 + j0);
        const float4 w1 = *reinterpret_cast<const float4*>(W2 + k * DH1 + j1);
        *reinterpret_cast<h8*>(&s_a[row][l][0]) =
            cat4(pk(w0.x, w0.y), pk(w0.z, w0.w),
                 pk(w1.x, w1.y), pk(w1.z, w1.w));
    }
    // Pre-GEMM A1-pack: lane-group 0 carries k-slots 0..3 = {wx,wy,wz,C*b1}
    // for row j' = m1*16 + (lane&15); all other groups/slots are zero.
    {
        const h2 z2 = pk(0.0f, 0.0f);
        #pragma unroll
        for (int v = 0; v < 2; ++v) {
            const int e  = v * 256 + t;       // 0..511
            const int m1 = e >> 6;
            const int l  = e & 63;
            const int gl = l >> 4;
            const int jp = m1 * 16 + (l & 15);
            h8 frag;
            if (gl == 0) {
                const float wx = W1[jp*3+0], wy = W1[jp*3+1], wz = W1[jp*3+2];
                frag = cat4(pk(wx, wy), pk(wz, CTANH * b1[jp]), z2, z2);
            } else {
                frag = cat4(z2, z2, z2, z2);
            }
            *reinterpret_cast<h8*>(&s_a1[m1][l][0]) = frag;
        }
    }
    if (t < DH1/2) {   // packed pair table: f32x4 written AND read
        const float wxe = W1[6*t+0], wye = W1[6*t+1], wze = W1[6*t+2];
        const float wxo = W1[6*t+3], wyo = W1[6*t+4], wzo = W1[6*t+5];
        const float qe  = -2.0f * (wxe*wxe + wye*wye + wze*wze);
        const float qo  = -2.0f * (wxo*wxo + wyo*wyo + wzo*wzo);
        f32x4 v;
        v[0] = pkf(wxe, wxo);
        v[1] = pkf(wye, wyo);
        v[2] = pkf(wze, wzo);
        v[3] = pkf(qe,  qo);
        s_wpk[t] = v;
    }
    if (t < DH2) { s_b2c[t] = CTANH * b2[t]; s_w3[t] = W3[t]; }
    __syncthreads();

    #pragma unroll 1
    for (int tile = 0; tile < TILES; ++tile) {
        const int tid = blockIdx.x + tile * gridDim.x;   // batch-tile index
        if (tid >= ntiles) break;
        const int braw = tid * 64 + wave * 16 + bcol;

        const float x0c = xv[tile][0] * CTANH;
        const float x1c = xv[tile][1] * CTANH;
        const float x2c = xv[tile][2] * CTANH;

        // B1 fragment for the pre-GEMM: k-slots 0..3 = {x0c,x1c,x2c,1} on
        // lane-group 0 only (matches A1's zero padding; k-map cancels).
        const h2 z2 = pk(0.0f, 0.0f);
        h2 xlo = z2, xhi = z2;
        if (g == 0) { xlo = pk(x0c, x1c); xhi = pk(x2c, 1.0f); }
        const h8 B1 = cat4(xlo, xhi, z2, z2);

        f32x4 acc[5][4];
        #pragma unroll
        for (int f = 0; f < 5; ++f)
            #pragma unroll
            for (int m = 0; m < 4; ++m)
                acc[f][m] = (f32x4){0.f, 0.f, 0.f, 0.f};

        #pragma unroll
        for (int kk = 0; kk < 4; ++kk) {
            // ---- pre via MFMA + jets for this lane's 8 j's ----
            h2 P0[4], P1[4], P2[4], P3[4], P4[4];
            #pragma unroll
            for (int u = 0; u < 2; ++u) {
                const int m1 = kk*2 + u;
                const h8 fa1 = *reinterpret_cast<const h8*>(&s_a1[m1][lane][0]);
                const f32x4 pr = __builtin_amdgcn_mfma_f32_16x16x32_f16(
                    fa1, B1, (f32x4){0.f, 0.f, 0.f, 0.f}, 0, 0, 0);
                // lane holds pre for j = m1*16 + g*4 + r (r=0..3), col=bcol
                #pragma unroll
                for (int v = 0; v < 2; ++v) {
                    const int pi = u*2 + v;
                    const f32x4 wp = s_wpk[m1*8 + g*2 + v];

                    const float prea = pr[v*2+0];
                    const float preb = pr[v*2+1];
                    const float ea   = __builtin_amdgcn_exp2f(prea);
                    const float ra   = __builtin_amdgcn_rcpf(ea + 1.0f);
                    const float ha   = fmaf(-2.0f, ra, 1.0f);
                    const float sa   = fmaf(-ha, ha, 1.0f);
                    const float eb   = __builtin_amdgcn_exp2f(preb);
                    const float rb   = __builtin_amdgcn_rcpf(eb + 1.0f);
                    const float hb   = fmaf(-2.0f, rb, 1.0f);
                    const float sb   = fmaf(-hb, hb, 1.0f);

                    const h2 S  = pk(sa, sb);
                    const h2 HS = pk(ha * sa, hb * sb);
                    P0[pi] = pk(ha, hb);
                    P1[pi] = pkmul(S,  wp[0]);   // v_pk_mul_f16 via asm
                    P2[pi] = pkmul(S,  wp[1]);
                    P3[pi] = pkmul(S,  wp[2]);
                    P4[pi] = pkmul(HS, wp[3]);
                }
            }
            const h8 F0 = cat4(P0[0], P0[1], P0[2], P0[3]);
            const h8 F1 = cat4(P1[0], P1[1], P1[2], P1[3]);
            const h8 F2 = cat4(P2[0], P2[1], P2[2], P2[3]);
            const h8 F3 = cat4(P3[0], P3[1], P3[2], P3[3]);
            const h8 F4 = cat4(P4[0], P4[1], P4[2], P4[3]);

            #pragma unroll
            for (int m = 0; m < 4; ++m) {
                const h8 fa = *reinterpret_cast<const h8*>(&s_a[kk*4 + m][lane][0]);
                acc[0][m] = __builtin_amdgcn_mfma_f32_16x16x32_f16(fa, F0, acc[0][m], 0, 0, 0);
                acc[1][m] = __builtin_amdgcn_mfma_f32_16x16x32_f16(fa, F1, acc[1][m], 0, 0, 0);
                acc[2][m] = __builtin_amdgcn_mfma_f32_16x16x32_f16(fa, F2, acc[2][m], 0, 0, 0);
                acc[3][m] = __builtin_amdgcn_mfma_f32_16x16x32_f16(fa, F3, acc[3][m], 0, 0, 0);
                acc[4][m] = __builtin_amdgcn_mfma_f32_16x16x32_f16(fa, F4, acc[4][m], 0, 0, 0);
            }
        }

        // ---- epilogue: lane holds k = m*16 + g*4 + r for its batch column ----
        float partial = 0.0f;
        #pragma unroll
        for (int m = 0; m < 4; ++m) {
            const int kb = m*16 + g*4;
            const f32x4 b2v = *reinterpret_cast<const f32x4*>(&s_b2c[kb]);
            const f32x4 w3v = *reinterpret_cast<const f32x4*>(&s_w3[kb]);
            #pragma unroll
            for (int r = 0; r < 4; ++r) {
                // g0 = tanh(z0 + b2): arg = C*acc + C*b2 (folded)
                const float e0 = __builtin_amdgcn_exp2f(fmaf(CTANH, acc[0][m][r], b2v[r]));
                const float g0 = fmaf(-2.0f, __builtin_amdgcn_rcpf(e0 + 1.0f), 1.0f);
                const float s2 = fmaf(-g0, g0, 1.0f);
                const float qd = acc[1][m][r]*acc[1][m][r]
                               + acc[2][m][r]*acc[2][m][r]
                               + acc[3][m][r]*acc[3][m][r];
                const float G2 = s2 * fmaf(-2.0f * g0, qd, acc[4][m][r]);
                partial = fmaf(w3v[r], G2, partial);
            }
        }

        partial += __shfl_xor(partial, 16);
        partial += __shfl_xor(partial, 32);

        if (g == 0 && braw < B) out[braw] = partial;
    }
}

extern "C" void kernel_launch(void* const* d_in, const int* in_sizes, int n_in,
                              void* d_out, int out_size, void* d_ws, size_t ws_size,
                              hipStream_t stream) {
    const float* x  = (const float*)d_in[0];
    const float* W1 = (const float*)d_in[1];
    const float* b1 = (const float*)d_in[2];
    const float* W2 = (const float*)d_in[3];
    const float* b2 = (const float*)d_in[4];
    const float* W3 = (const float*)d_in[5];
    // d_in[6] = b3: does not enter the 2nd Taylor coefficient.
    float* out = (float*)d_out;

    const int B      = in_sizes[0] / 3;
    const int ntiles = (B + 63) / 64;                // 64 batch per tile
    const int grid   = (ntiles + TILES - 1) / TILES; // ~512 blocks
    lap_fused<<<grid, BLOCK, 0, stream>>>(x, W1, b1, W2, b2, W3, out, B, ntiles);
}